// Round 15
// baseline (1949.152 us; speedup 1.0000x reference)
//
#include <hip/hip_runtime.h>
#include <hip/hip_bf16.h>

#define B_ 64
#define N_ 1000
#define NP 1024
#define D_ 256
#define L_ 7
#define MP (B_*NP)        // 65536 padded rows total
#define PKB 262144        // u16 elements per batch in packed operand buffers

typedef unsigned short u16;
typedef __attribute__((ext_vector_type(4))) float f32x4;
typedef __bf16 bf16x8 __attribute__((ext_vector_type(8)));

static __device__ __forceinline__ u16 f2bf(float f) {
  __hip_bfloat16 h = __float2bfloat16(f);
  return *reinterpret_cast<u16*>(&h);
}
static __device__ __forceinline__ float bf2f(u16 u) {
  __hip_bfloat16 h;
  *reinterpret_cast<u16*>(&h) = u;
  return __bfloat162float(h);
}

// async global->LDS 16B copy: LDS dest is wave-uniform base (HW adds lane*16)
static __device__ __forceinline__ void gl_lds16(const u16* g, u16* l) {
  __builtin_amdgcn_global_load_lds(
      (const __attribute__((address_space(1))) void*)g,
      (__attribute__((address_space(3))) void*)l, 16, 0, 0);
}

// ---------------- pack adjacency into bitmask (diag forced on) ----------------
__global__ __launch_bounds__(64) void pack_mask_k(const float* __restrict__ adj,
                                                  unsigned long long* __restrict__ mask) {
  int row = blockIdx.x;              // b*N_ + i
  int b = row / N_, i = row - b * N_;
  int lane = threadIdx.x;            // 64 threads
  const float* arow = adj + (size_t)(b * N_ + i) * N_;
  #pragma unroll
  for (int j0 = 0; j0 < NP; j0 += 64) {
    int j = j0 + lane;
    bool on = (j < N_) && (arow[j] != 0.0f || j == i);
    unsigned long long m = __ballot(on);
    if (lane == 0) mask[((size_t)(b * NP + i)) * 16 + (j0 >> 6)] = m;
  }
}

// ---------------- convert weights to bf16 in MFMA-fragment-packed layout ----------------
__global__ __launch_bounds__(256) void conv_w_k(const float* __restrict__ Wa,
                                                const float* __restrict__ W0,
                                                const float* __restrict__ W1,
                                                const float* __restrict__ Wf,
                                                u16* __restrict__ wpk) {
  int T = blockIdx.x * 256 + threadIdx.x;   // one 16B frag-slot
  const int NW = 3 * L_ + 1;
  if (T >= NW * 128 * 64) return;
  int lane = T & 63;
  int fid = T >> 6;
  int k = fid & 7, f = (fid >> 3) & 3, by = (fid >> 5) & 3, w = fid >> 7;
  const float* src;
  if (w < L_) src = Wa + (size_t)w * D_ * D_;
  else if (w < 2 * L_) src = W0 + (size_t)(w - L_) * D_ * D_;
  else if (w < 3 * L_) src = W1 + (size_t)(w - 2 * L_) * D_ * D_;
  else src = Wf;
  int row = by * 64 + f * 16 + (lane & 15);
  int col = k * 32 + ((lane >> 4) << 3);
  const float* s = src + (size_t)row * D_ + col;
  u16 out8[8];
  #pragma unroll
  for (int e = 0; e < 8; e++) out8[e] = f2bf(s[e]);
  *reinterpret_cast<bf16x8*>(wpk + (size_t)T * 8) =
      *reinterpret_cast<bf16x8*>(out8);
}

// ---------------- copy input x into padded fp32 + bf16, zero pad rows ----------------
__global__ __launch_bounds__(256) void prep_x_k(const float* __restrict__ x,
                                                float* __restrict__ xc,
                                                u16* __restrict__ xb) {
  size_t t = (size_t)blockIdx.x * blockDim.x + threadIdx.x;
  const size_t total = (size_t)B_ * N_ * D_;
  if (t < total) {
    int b = (int)(t / (N_ * D_));
    int rem = (int)(t - (size_t)b * (N_ * D_));
    size_t o = (size_t)b * NP * D_ + rem;
    float v = x[t];
    xc[o] = v;
    xb[o] = f2bf(v);
  }
  const size_t padTotal = (size_t)B_ * (NP - N_) * D_;
  if (t < padTotal) {
    int b = (int)(t / ((NP - N_) * D_));
    int rem = (int)(t - (size_t)b * ((NP - N_) * D_));
    size_t o = (size_t)b * NP * D_ + (size_t)N_ * D_ + rem;
    xc[o] = 0.f;
    xb[o] = 0;
  }
}

// ---------------- prologue pack: xb -> xpk (QK B / linear A frags) ----------------
__global__ __launch_bounds__(256) void pack_x_k(const u16* __restrict__ xb,
                                                u16* __restrict__ xpk) {
  __shared__ u16 t[64][65];
  int b = blockIdx.z;
  int cc = blockIdx.x;               // j-chunk index (16)
  int bd = blockIdx.y;               // 64-wide d block (4)
  int i0 = cc * 64, d0 = bd * 64;
  int tid = threadIdx.x;
  int tx = tid & 63, ty = tid >> 6;
  const u16* src = xb + (size_t)b * NP * D_;
  #pragma unroll
  for (int r = ty; r < 64; r += 4)
    t[r][tx] = src[(size_t)(i0 + r) * D_ + d0 + tx];   // t[j-local][d-local]
  __syncthreads();
  int lane = tid & 63, q = tid >> 6;
  int l4 = lane >> 4, l15 = lane & 15;
  u16* dstq = xpk + (size_t)b * PKB;
  #pragma unroll
  for (int kk = 0; kk < 2; kk++) {
    int frag = cc * 32 + q * 8 + (2 * bd + kk);
    bf16x8 v;
    #pragma unroll
    for (int e = 0; e < 8; e++)
      v[e] = *reinterpret_cast<const __bf16*>(&t[l15 + 16 * q][kk * 32 + (l4 << 3) + e]);
    *reinterpret_cast<bf16x8*>(dstq + (size_t)frag * 512 + lane * 8) = v;
  }
}

// ---------------- generic linear: y = A @ W.T + bias (W fragment-packed) ----------------
// MODE 4: A-frag-packed out (q). APK: A fragment-packed. (Only used for layer-0 q.)
template <int MODE, int APK>
__global__ __launch_bounds__(256) void linear_k(const u16* __restrict__ A,
                                                const u16* __restrict__ W,   // packed
                                                const float* __restrict__ bias,
                                                u16* __restrict__ outb,
                                                float* __restrict__ xc,
                                                u16* __restrict__ xbp,
                                                float* __restrict__ outf) {
  int lane = threadIdx.x & 63;
  int wv = threadIdx.x >> 6;
  int rbase = blockIdx.x * 64 + wv * 16;
  int cbase = blockIdx.y * 64;
  f32x4 acc[4] = {};
  const u16* Ar;
  if (APK) Ar = A + ((size_t)(rbase >> 4) << 12) + lane * 8;
  else     Ar = A + (size_t)(rbase + (lane & 15)) * D_ + ((lane >> 4) << 3);
  const u16* Wr = W + (size_t)blockIdx.y * (32 * 512) + lane * 8;   // coalesced frags
  #pragma unroll
  for (int k = 0; k < 8; k++) {
    bf16x8 a = APK ? *reinterpret_cast<const bf16x8*>(Ar + k * 512)
                   : *reinterpret_cast<const bf16x8*>(Ar + k * 32);
    #pragma unroll
    for (int f = 0; f < 4; f++) {
      bf16x8 bb = *reinterpret_cast<const bf16x8*>(Wr + (f * 8 + k) * 512);
      acc[f] = __builtin_amdgcn_mfma_f32_16x16x32_bf16(a, bb, acc[f], 0, 0, 0);
    }
  }
  int r0 = rbase + ((lane >> 4) << 2);
  int col = cbase + (lane & 15);
  #pragma unroll
  for (int f = 0; f < 4; f++) {
    int c = col + f * 16;
    float bv = bias[c];
    #pragma unroll
    for (int r = 0; r < 4; r++) {
      int row = r0 + r;
      float v = acc[f][r] + bv;
      if (MODE == 3) {
        int b = row >> 10, i = row & (NP - 1);
        if (i < N_) outf[((size_t)b * N_ + i) * D_ + c] = v;
      } else {  // MODE 4
        size_t dst = ((size_t)(row >> 4) << 12) + ((c >> 5) << 9) +
                     ((((c >> 3) & 3) * 16 + (row & 15)) << 3) + (c & 7);
        outb[dst] = f2bf(v);
      }
    }
  }
}

// ---------------- fused MLP + next-layer q (or final output) ----------------
// R22 structure; R25: pvpk deferred scatter removed (buffer eliminated).
template <int FINAL>
__global__ __launch_bounds__(256) void mlp_fused_k(const u16* __restrict__ A,
                                                   const u16* __restrict__ W0p,
                                                   const float* __restrict__ bias0,
                                                   const u16* __restrict__ W1p,
                                                   const float* __restrict__ bias1,
                                                   u16* __restrict__ xpk,
                                                   float* __restrict__ xc,
                                                   const u16* __restrict__ Wqp,
                                                   const float* __restrict__ biasq,
                                                   u16* __restrict__ qpk,
                                                   float* __restrict__ outf) {
  __shared__ u16 h0lds[8192];    // h0: 32 rows x 256 cols, A-frag layout (16KB)
  __shared__ u16 xnlds[8192];    // x_new: same layout (16KB)
  int blk = blockIdx.x;          // 2048 = MP/32
  int lane = threadIdx.x & 63;
  int wv = threadIdx.x >> 6;     // 0..3
  int rsub = wv & 1, ch = wv >> 1;
  int l15 = lane & 15, l4 = lane >> 4;

  // ---- GEMM1: rows rsub*16..+16, cols ch*128..+128, two 64-col halves ----
  const u16* Ar = A + (size_t)(blk * 32 + rsub * 16 + l15) * D_ + (l4 << 3);
  const u16* w0b = W0p + (size_t)(ch * 64) * 512 + lane * 8;
  #pragma unroll
  for (int hf = 0; hf < 2; hf++) {
    f32x4 acc1[4] = {};
    __builtin_amdgcn_s_setprio(1);
    #pragma unroll
    for (int k = 0; k < 8; k++) {
      bf16x8 a = *reinterpret_cast<const bf16x8*>(Ar + k * 32);
      #pragma unroll
      for (int ff = 0; ff < 4; ff++) {
        bf16x8 bb = *reinterpret_cast<const bf16x8*>(
            w0b + (hf * 32 + ff * 8 + k) * 512);
        acc1[ff] = __builtin_amdgcn_mfma_f32_16x16x32_bf16(a, bb, acc1[ff], 0, 0, 0);
      }
    }
    __builtin_amdgcn_s_setprio(0);
    // h0 = relu(acc1 + b0) -> h0lds in A-frag layout (static offsets)
    #pragma unroll
    for (int ff = 0; ff < 4; ff++) {
      int fc = hf * 4 + ff;
      int c = ch * 128 + fc * 16 + l15;
      float bv = bias0[c];
      int base = rsub * 4096 + (ch * 4 + (fc >> 1)) * 512 +
                 (((fc * 2 + (l15 >> 3)) & 3) * 16 + l4 * 4) * 8 + (l15 & 7);
      #pragma unroll
      for (int r = 0; r < 4; r++)
        h0lds[base + r * 8] = f2bf(fmaxf(acc1[ff][r] + bv, 0.f));
    }
  }
  __syncthreads();

  // ---- GEMM2 + light epilogue: xc residual + xnlds only ----
  const u16* w1b = W1p + (size_t)(ch * 64) * 512 + lane * 8;
  int r0g = blk * 32 + rsub * 16 + l4 * 4;
  #pragma unroll
  for (int hf = 0; hf < 2; hf++) {
    f32x4 acc2[4] = {};
    __builtin_amdgcn_s_setprio(1);
    #pragma unroll
    for (int k = 0; k < 8; k++) {
      bf16x8 a = *reinterpret_cast<const bf16x8*>(&h0lds[rsub * 4096 + k * 512 + lane * 8]);
      #pragma unroll
      for (int ff = 0; ff < 4; ff++) {
        bf16x8 bb = *reinterpret_cast<const bf16x8*>(
            w1b + (hf * 32 + ff * 8 + k) * 512);
        acc2[ff] = __builtin_amdgcn_mfma_f32_16x16x32_bf16(a, bb, acc2[ff], 0, 0, 0);
      }
    }
    __builtin_amdgcn_s_setprio(0);
    #pragma unroll
    for (int ff = 0; ff < 4; ff++) {
      int fc = hf * 4 + ff;
      int c = ch * 128 + fc * 16 + l15;
      float bv = bias1[c];
      int base = rsub * 4096 + (ch * 4 + (fc >> 1)) * 512 +
                 (((fc * 2 + (l15 >> 3)) & 3) * 16 + l4 * 4) * 8 + (l15 & 7);
      #pragma unroll
      for (int r = 0; r < 4; r++) {
        int row = r0g + r;
        float v = fmaxf(acc2[ff][r] + bv, 0.f);
        size_t o = (size_t)row * D_ + c;
        float nv = v + xc[o];
        if (!FINAL) xc[o] = nv;
        xnlds[base + r * 8] = f2bf(nv);
      }
    }
  }
  __syncthreads();

  // ---- deferred xpk copy (verbatim linear: xpk[blk<<13 + i] == xnlds[i]) ----
  if (!FINAL) {
    int tid = threadIdx.x;
    u16* dst = xpk + ((size_t)blk << 13) + tid * 8;
    #pragma unroll
    for (int i = 0; i < 4; i++)
      *reinterpret_cast<bf16x8*>(dst + i * 2048) =
          *reinterpret_cast<const bf16x8*>(&xnlds[tid * 8 + i * 2048]);
  }

  // ---- GEMM3: q(l+1) = x_new @ Wq^T + bq (or FINAL: out = x_new @ Wf^T + bf) ----
  const u16* wqb = Wqp + (size_t)(ch * 64) * 512 + lane * 8;
  #pragma unroll
  for (int hf = 0; hf < 2; hf++) {
    f32x4 acc3[4] = {};
    __builtin_amdgcn_s_setprio(1);
    #pragma unroll
    for (int k = 0; k < 8; k++) {
      bf16x8 a = *reinterpret_cast<const bf16x8*>(&xnlds[rsub * 4096 + k * 512 + lane * 8]);
      #pragma unroll
      for (int ff = 0; ff < 4; ff++) {
        bf16x8 bb = *reinterpret_cast<const bf16x8*>(
            wqb + (hf * 32 + ff * 8 + k) * 512);
        acc3[ff] = __builtin_amdgcn_mfma_f32_16x16x32_bf16(a, bb, acc3[ff], 0, 0, 0);
      }
    }
    __builtin_amdgcn_s_setprio(0);
    #pragma unroll
    for (int ff = 0; ff < 4; ff++) {
      int fc = hf * 4 + ff;
      int c = ch * 128 + fc * 16 + l15;
      float bv = biasq[c];
      #pragma unroll
      for (int r = 0; r < 4; r++) {
        int row = r0g + r;
        float v = acc3[ff][r] + bv;
        if (FINAL) {
          int b = row >> 10, i = row & (NP - 1);
          if (i < N_) outf[((size_t)b * N_ + i) * D_ + c] = v;
        } else {
          size_t dst = ((size_t)(row >> 4) << 12) + ((c >> 5) << 9) +
                       ((((c >> 3) & 3) * 16 + (row & 15)) << 3) + (c & 7);
          qpk[dst] = f2bf(v);
        }
      }
    }
  }
}

// ---------------- fused attention: Y = (mask*(sigmoid(q x^T)+eps*I)) @ x / rowsum ----------
// R26 = R25 minus qlds. R21 proved q-staging perf-neutral (global-q R15 = 148,
// qlds R21 = 148): qlds' only effect is 32KB of LDS. Dropping it: LDS = xlds
// 32K + plds 8K = 40960B -> 4 blocks/CU = 32 waves/CU (2x residency). In a
// ~70%-stall kernel (3 barriers/iter + LDS-pipe + memory latency), doubled
// independent blocks double cross-barrier overlap — the one lever never yet
// isolated. QK A-operand = R15-proven qpkB global pattern (lane*8, unswizzled).
// xlds swizzle / PV gather / sigmoid / barriers byte-identical to R25.
__global__ __launch_bounds__(512) void attn_fused_k(const u16* __restrict__ qpk,
                                                    const u16* __restrict__ xpk,
                                                    const unsigned long long* __restrict__ mask,
                                                    u16* __restrict__ yb) {
  __shared__ u16 xlds[16384];          // staged xpk chunk (32KB), swizzled units
  __shared__ u16 plds[64][64];         // P single buffer, XOR-swizzled cols (8KB)
  float* dlds = (float*)xlds;          // den partials (aliases xlds, dead after loop)
  int wg = blockIdx.x;                 // 1024 = 64 b * 16 row-blocks
  int xcd = wg & 7, slot = wg >> 3;    // bijective XCD swizzle (1024 % 8 == 0)
  int b = xcd * 8 + (slot >> 4);       // 8 batches per XCD, 16 blocks/batch adjacent
  int rb = slot & 15;
  int rbase = rb * 64;
  int lane = threadIdx.x & 63;
  int wv = threadIdx.x >> 6;           // 0..7
  int rsub = wv & 3, jh = wv >> 2;     // row-subtile (16 rows), j-half (32 cols)
  int l15 = lane & 15, l4 = lane >> 4;
  int rowL = rsub * 16 + l4 * 4;       // local row base owned for sigmoid

  const u16* qpkB = qpk + ((((size_t)b * NP + rbase + rsub * 16) >> 4) << 12) + lane * 8;
  const u16* xpkC = xpk + (size_t)b * PKB;
  const unsigned long long* mB = mask + (size_t)b * (NP * 16);
  // plds swizzled read bases (constant per thread): col ^ ((row&7)<<3), row = rt*16+l15
  int swr = (l15 & 7) << 3;
  int pc0 = (l4 << 3) ^ swr;           // j-half 0 (kk=0)
  int pc1 = (32 | (l4 << 3)) ^ swr;    // j-half 1 (kk=1)
  // swizzled lane offset for staging source + QK B reads (u16 units)
  int loff = 8 * (lane ^ (lane >> 3));
  // PV gather bases: logical = pvb + kk*8192 + ct*256 + e*8; phys = log^(x3<<3),
  // x3 = bits[8:6] = (lane>>4&1) | (((lane&15)>>3)<<1) | (ct<<2). Fold: G^(e*8).
  int pvb = ((lane >> 5) & 1) * 4096 + (wv >> 1) * 1024 + (wv & 1) * 512 +
            ((lane & 15) >> 3) * 128 + ((lane >> 4) & 1) * 64 + (lane & 7);
  int x3 = ((lane >> 4) & 1) | (((lane & 15) >> 3) << 1);
  int G00 = pvb + (x3 << 3);                    // kk0 ct0
  int G01 = pvb + 256 + ((x3 ^ 4) << 3);        // kk0 ct1
  int G10 = G00 + 8192;                         // kk1 ct0
  int G11 = G01 + 8192;                         // kk1 ct1

  f32x4 yacc[4][2] = {};               // [row-tile][col-tile], 64 rows x 32 cols
  float denp[4] = {0.f, 0.f, 0.f, 0.f};

  // ---- prologue: stage chunk 0 (pre-swizzled source lanes) ----
  {
    const u16* gs = xpkC + wv * 2048 + loff;
    u16* ld = &xlds[wv * 2048];
    #pragma unroll
    for (int i = 0; i < 4; i++)
      gl_lds16(gs + i * 512, ld + i * 512);
  }
  __syncthreads();   // drains vmcnt -> xlds ready

  #pragma unroll 1
  for (int t = 0; t < 16; t++) {
    // ---- QK(t): my 16 rows x 32 j, A from global q, B from xlds (loff) ----
    f32x4 sacc[2] = {};
    __builtin_amdgcn_s_setprio(1);
    #pragma unroll
    for (int k = 0; k < 8; k++) {
      bf16x8 a = *reinterpret_cast<const bf16x8*>(qpkB + k * 512);
      bf16x8 b0 = *reinterpret_cast<const bf16x8*>(&xlds[(16 * jh + k) * 512 + loff]);
      sacc[0] = __builtin_amdgcn_mfma_f32_16x16x32_bf16(a, b0, sacc[0], 0, 0, 0);
      bf16x8 b1 = *reinterpret_cast<const bf16x8*>(&xlds[(16 * jh + 8 + k) * 512 + loff]);
      sacc[1] = __builtin_amdgcn_mfma_f32_16x16x32_bf16(a, b1, sacc[1], 0, 0, 0);
    }
    __builtin_amdgcn_s_setprio(0);
    // ---- sigmoid + mask + eps-diag -> bf16 P in plds (swizzled) + den ----
    #pragma unroll
    for (int r = 0; r < 4; r++) {
      int i = rbase + rowL + r;
      unsigned long long mw = (i < N_) ? mB[((size_t)i << 4) + t] : 0ull;
      int swz = ((rowL + r) & 7) << 3;
      #pragma unroll
      for (int fl = 0; fl < 2; fl++) {
        int jloc = jh * 32 + fl * 16 + l15;
        int j = t * 64 + jloc;
        float w = 0.f;
        if ((mw >> jloc) & 1ull) {
          float s = __builtin_amdgcn_rcpf(1.f + __expf(-sacc[fl][r]));
          w = s + (i == j ? 1e-5f : 0.f);
        }
        u16 wq = f2bf(w);
        plds[rowL + r][jloc ^ swz] = wq;
        denp[r] += bf2f(wq);
      }
    }
    __syncthreads();   // A: plds published (all QK xlds reads also done)
    // ---- PV(t): all 64 rows, my 32 d-cols; B-frags gathered from xlds ----
    {
      const __bf16* xb16 = reinterpret_cast<const __bf16*>(xlds);
      __builtin_amdgcn_s_setprio(1);
      bf16x8 w0, w1;
      #pragma unroll
      for (int e = 0; e < 8; e++) {
        w0[e] = xb16[G00 ^ (e * 8)];
        w1[e] = xb16[G01 ^ (e * 8)];
      }
      #pragma unroll
      for (int rt = 0; rt < 4; rt++) {
        bf16x8 ap = *reinterpret_cast<const bf16x8*>(&plds[rt * 16 + l15][pc0]);
        yacc[rt][0] = __builtin_amdgcn_mfma_f32_16x16x32_bf16(ap, w0, yacc[rt][0], 0, 0, 0);
        yacc[rt][1] = __builtin_amdgcn_mfma_f32_16x16x32_bf16(ap, w1, yacc[rt][1], 0, 0, 0);
      }
      #pragma unroll
      for (int e = 0; e < 8; e++) {
        w0[e] = xb16[G10 ^ (e * 8)];
        w1[e] = xb16[G11 ^ (e * 8)];
      }
      #pragma unroll
      for (int rt = 0; rt < 4; rt++) {
        bf16x8 ap = *reinterpret_cast<const bf16x8*>(&plds[rt * 16 + l15][pc1]);
        yacc[rt][0] = __builtin_amdgcn_mfma_f32_16x16x32_bf16(ap, w0, yacc[rt][0], 0, 0, 0);
        yacc[rt][1] = __builtin_amdgcn_mfma_f32_16x16x32_bf16(ap, w1, yacc[rt][1], 0, 0, 0);
      }
      __builtin_amdgcn_s_setprio(0);
    }
    __syncthreads();   // B: all PV xlds/plds reads done -> xlds safe to overwrite
    // ---- stage chunk t+1 into xlds (pre-swizzled source lanes) ----
    if (t < 15) {
      const u16* gs = xpkC + (size_t)(t + 1) * 16384 + wv * 2048 + loff;
      u16* ld = &xlds[wv * 2048];
      #pragma unroll
      for (int i = 0; i < 4; i++)
        gl_lds16(gs + i * 512, ld + i * 512);
    }
    __syncthreads();   // C: drains vmcnt -> xlds = chunk t+1 ready; plds reusable
  }

  // ---- den: 16-lane reduce per wave -> cross-wave (jh=0/1) sum via dlds ----
  #pragma unroll
  for (int r = 0; r < 4; r++) {
    float d = denp[r];
    #pragma unroll
    for (int m = 1; m < 16; m <<= 1) d += __shfl_xor(d, m, 64);
    if (l15 == 0) dlds[wv * 16 + l4 * 4 + r] = d;
  }
  __syncthreads();
  // ---- epilogue: row-major bf16 out, my 32 d-cols of all 64 rows ----
  u16* yB = yb + ((size_t)b * NP + rbase) * D_ + wv * 32 + l15;
  #pragma unroll
  for (int rt = 0; rt < 4; rt++) {
    #pragma unroll
    for (int r = 0; r < 4; r++) {
      int rl = rt * 16 + l4 * 4 + r;
      int i = rbase + rl;
      float den = dlds[rt * 16 + l4 * 4 + r] + dlds[(rt + 4) * 16 + l4 * 4 + r];
      float inv = (i < N_ && den > 0.f) ? 1.f / den : 0.f;
      #pragma unroll
      for (int ct = 0; ct < 2; ct++)
        yB[(size_t)rl * D_ + ct * 16] = f2bf(yacc[rt][ct][r] * inv);
    }
  }
}

extern "C" void kernel_launch(void* const* d_in, const int* in_sizes, int n_in,
                              void* d_out, int out_size, void* d_ws, size_t ws_size,
                              hipStream_t stream) {
  const float* x   = (const float*)d_in[0];
  const float* adj = (const float*)d_in[1];
  const float* Wa  = (const float*)d_in[2];
  const float* ba  = (const float*)d_in[3];
  const float* W0  = (const float*)d_in[4];
  const float* b0_ = (const float*)d_in[5];
  const float* W1  = (const float*)d_in[6];
  const float* b1_ = (const float*)d_in[7];
  const float* Wf  = (const float*)d_in[8];
  const float* bff = (const float*)d_in[9];
  float* out = (float*)d_out;

  char* p = (char*)d_ws;
  auto alloc = [&](size_t bytes) {
    char* r = p;
    p += (bytes + 255) & ~(size_t)255;
    return r;
  };
  unsigned long long* mask = (unsigned long long*)alloc((size_t)B_ * NP * 16 * 8);
  u16* xb    = (u16*)alloc((size_t)MP * D_ * 2);   // prologue only
  u16* xpk   = (u16*)alloc((size_t)B_ * PKB * 2);  // x: QK-B frags == linear-A frags
  u16* qpk   = (u16*)alloc((size_t)MP * D_ * 2);   // q, A-frag-packed
  u16* slotB = (u16*)alloc((size_t)MP * D_ * 2);   // attn out, row-major
  float* xc  = (float*)alloc((size_t)MP * D_ * 4);
  u16* wb    = (u16*)alloc((size_t)(3 * L_ + 1) * D_ * D_ * 2);

  pack_mask_k<<<dim3(B_ * N_), dim3(64), 0, stream>>>(adj, mask);
  conv_w_k<<<dim3(704), dim3(256), 0, stream>>>(Wa, W0, W1, Wf, wb);
  prep_x_k<<<dim3((B_ * N_ * D_ + 255) / 256), dim3(256), 0, stream>>>(x, xc, xb);
  pack_x_k<<<dim3(16, 4, B_), dim3(256), 0, stream>>>(xb, xpk);

  // q for layer 0
  linear_k<4, 1><<<dim3(MP / 64, D_ / 64), dim3(256), 0, stream>>>(
      xpk, wb, ba, qpk, nullptr, nullptr, nullptr);

  for (int l = 0; l < L_; l++) {
    const u16* w0l = wb + (size_t)(L_ + l) * D_ * D_;
    const u16* w1l = wb + (size_t)(2 * L_ + l) * D_ * D_;

    attn_fused_k<<<dim3(1024), dim3(512), 0, stream>>>(
        qpk, xpk, mask, slotB);
    if (l < L_ - 1) {
      mlp_fused_k<0><<<dim3(2048), dim3(256), 0, stream>>>(
          slotB, w0l, b0_ + l * D_, w1l, b1_ + l * D_, xpk, xc,
          wb + (size_t)(l + 1) * D_ * D_, ba + (l + 1) * D_, qpk, nullptr);
    } else {
      mlp_fused_k<1><<<dim3(2048), dim3(256), 0, stream>>>(
          slotB, w0l, b0_ + l * D_, w1l, b1_ + l * D_, xpk, xc,
          wb + (size_t)3 * L_ * D_ * D_, bff, nullptr, out);
    }
  }
}

// Round 16
// 1555.874 us; speedup vs baseline: 1.2528x; 1.2528x over previous
//
#include <hip/hip_runtime.h>
#include <hip/hip_bf16.h>

#define B_ 64
#define N_ 1000
#define NP 1024
#define D_ 256
#define L_ 7
#define MP (B_*NP)        // 65536 padded rows total
#define PKB 262144        // u16 elements per batch in packed operand buffers

typedef unsigned short u16;
typedef __attribute__((ext_vector_type(4))) float f32x4;
typedef __bf16 bf16x8 __attribute__((ext_vector_type(8)));

static __device__ __forceinline__ u16 f2bf(float f) {
  __hip_bfloat16 h = __float2bfloat16(f);
  return *reinterpret_cast<u16*>(&h);
}
static __device__ __forceinline__ float bf2f(u16 u) {
  __hip_bfloat16 h;
  *reinterpret_cast<u16*>(&h) = u;
  return __bfloat162float(h);
}

// async global->LDS 16B copy: LDS dest is wave-uniform base (HW adds lane*16)
static __device__ __forceinline__ void gl_lds16(const u16* g, u16* l) {
  __builtin_amdgcn_global_load_lds(
      (const __attribute__((address_space(1))) void*)g,
      (__attribute__((address_space(3))) void*)l, 16, 0, 0);
}

// ---------------- pack adjacency into bitmask (diag forced on) ----------------
__global__ __launch_bounds__(64) void pack_mask_k(const float* __restrict__ adj,
                                                  unsigned long long* __restrict__ mask) {
  int row = blockIdx.x;              // b*N_ + i
  int b = row / N_, i = row - b * N_;
  int lane = threadIdx.x;            // 64 threads
  const float* arow = adj + (size_t)(b * N_ + i) * N_;
  #pragma unroll
  for (int j0 = 0; j0 < NP; j0 += 64) {
    int j = j0 + lane;
    bool on = (j < N_) && (arow[j] != 0.0f || j == i);
    unsigned long long m = __ballot(on);
    if (lane == 0) mask[((size_t)(b * NP + i)) * 16 + (j0 >> 6)] = m;
  }
}

// ---------------- convert weights to bf16 in MFMA-fragment-packed layout ----------------
__global__ __launch_bounds__(256) void conv_w_k(const float* __restrict__ Wa,
                                                const float* __restrict__ W0,
                                                const float* __restrict__ W1,
                                                const float* __restrict__ Wf,
                                                u16* __restrict__ wpk) {
  int T = blockIdx.x * 256 + threadIdx.x;   // one 16B frag-slot
  const int NW = 3 * L_ + 1;
  if (T >= NW * 128 * 64) return;
  int lane = T & 63;
  int fid = T >> 6;
  int k = fid & 7, f = (fid >> 3) & 3, by = (fid >> 5) & 3, w = fid >> 7;
  const float* src;
  if (w < L_) src = Wa + (size_t)w * D_ * D_;
  else if (w < 2 * L_) src = W0 + (size_t)(w - L_) * D_ * D_;
  else if (w < 3 * L_) src = W1 + (size_t)(w - 2 * L_) * D_ * D_;
  else src = Wf;
  int row = by * 64 + f * 16 + (lane & 15);
  int col = k * 32 + ((lane >> 4) << 3);
  const float* s = src + (size_t)row * D_ + col;
  u16 out8[8];
  #pragma unroll
  for (int e = 0; e < 8; e++) out8[e] = f2bf(s[e]);
  *reinterpret_cast<bf16x8*>(wpk + (size_t)T * 8) =
      *reinterpret_cast<bf16x8*>(out8);
}

// ---------------- copy input x into padded fp32 + bf16, zero pad rows ----------------
__global__ __launch_bounds__(256) void prep_x_k(const float* __restrict__ x,
                                                float* __restrict__ xc,
                                                u16* __restrict__ xb) {
  size_t t = (size_t)blockIdx.x * blockDim.x + threadIdx.x;
  const size_t total = (size_t)B_ * N_ * D_;
  if (t < total) {
    int b = (int)(t / (N_ * D_));
    int rem = (int)(t - (size_t)b * (N_ * D_));
    size_t o = (size_t)b * NP * D_ + rem;
    float v = x[t];
    xc[o] = v;
    xb[o] = f2bf(v);
  }
  const size_t padTotal = (size_t)B_ * (NP - N_) * D_;
  if (t < padTotal) {
    int b = (int)(t / ((NP - N_) * D_));
    int rem = (int)(t - (size_t)b * ((NP - N_) * D_));
    size_t o = (size_t)b * NP * D_ + (size_t)N_ * D_ + rem;
    xc[o] = 0.f;
    xb[o] = 0;
  }
}

// ---------------- prologue pack: xb -> xpk (QK B / linear A frags) ----------------
// pvpk eliminated (R25): PV B-frags are gathered from the staged xlds chunk
// inside attn (x^T was redundant data).
__global__ __launch_bounds__(256) void pack_x_k(const u16* __restrict__ xb,
                                                u16* __restrict__ xpk) {
  __shared__ u16 t[64][65];
  int b = blockIdx.z;
  int cc = blockIdx.x;               // j-chunk index (16)
  int bd = blockIdx.y;               // 64-wide d block (4)
  int i0 = cc * 64, d0 = bd * 64;
  int tid = threadIdx.x;
  int tx = tid & 63, ty = tid >> 6;
  const u16* src = xb + (size_t)b * NP * D_;
  #pragma unroll
  for (int r = ty; r < 64; r += 4)
    t[r][tx] = src[(size_t)(i0 + r) * D_ + d0 + tx];   // t[j-local][d-local]
  __syncthreads();
  int lane = tid & 63, q = tid >> 6;
  int l4 = lane >> 4, l15 = lane & 15;
  u16* dstq = xpk + (size_t)b * PKB;
  #pragma unroll
  for (int kk = 0; kk < 2; kk++) {
    int frag = cc * 32 + q * 8 + (2 * bd + kk);
    bf16x8 v;
    #pragma unroll
    for (int e = 0; e < 8; e++)
      v[e] = *reinterpret_cast<const __bf16*>(&t[l15 + 16 * q][kk * 32 + (l4 << 3) + e]);
    *reinterpret_cast<bf16x8*>(dstq + (size_t)frag * 512 + lane * 8) = v;
  }
}

// ---------------- generic linear: y = A @ W.T + bias (W fragment-packed) ----------------
// MODE 4: A-frag-packed out (q). APK: A fragment-packed. (Only used for layer-0 q.)
template <int MODE, int APK>
__global__ __launch_bounds__(256) void linear_k(const u16* __restrict__ A,
                                                const u16* __restrict__ W,   // packed
                                                const float* __restrict__ bias,
                                                u16* __restrict__ outb,
                                                float* __restrict__ xc,
                                                u16* __restrict__ xbp,
                                                float* __restrict__ outf) {
  int lane = threadIdx.x & 63;
  int wv = threadIdx.x >> 6;
  int rbase = blockIdx.x * 64 + wv * 16;
  int cbase = blockIdx.y * 64;
  f32x4 acc[4] = {};
  const u16* Ar;
  if (APK) Ar = A + ((size_t)(rbase >> 4) << 12) + lane * 8;
  else     Ar = A + (size_t)(rbase + (lane & 15)) * D_ + ((lane >> 4) << 3);
  const u16* Wr = W + (size_t)blockIdx.y * (32 * 512) + lane * 8;   // coalesced frags
  #pragma unroll
  for (int k = 0; k < 8; k++) {
    bf16x8 a = APK ? *reinterpret_cast<const bf16x8*>(Ar + k * 512)
                   : *reinterpret_cast<const bf16x8*>(Ar + k * 32);
    #pragma unroll
    for (int f = 0; f < 4; f++) {
      bf16x8 bb = *reinterpret_cast<const bf16x8*>(Wr + (f * 8 + k) * 512);
      acc[f] = __builtin_amdgcn_mfma_f32_16x16x32_bf16(a, bb, acc[f], 0, 0, 0);
    }
  }
  int r0 = rbase + ((lane >> 4) << 2);
  int col = cbase + (lane & 15);
  #pragma unroll
  for (int f = 0; f < 4; f++) {
    int c = col + f * 16;
    float bv = bias[c];
    #pragma unroll
    for (int r = 0; r < 4; r++) {
      int row = r0 + r;
      float v = acc[f][r] + bv;
      if (MODE == 3) {
        int b = row >> 10, i = row & (NP - 1);
        if (i < N_) outf[((size_t)b * N_ + i) * D_ + c] = v;
      } else {  // MODE 4
        size_t dst = ((size_t)(row >> 4) << 12) + ((c >> 5) << 9) +
                     ((((c >> 3) & 3) * 16 + (row & 15)) << 3) + (c & 7);
        outb[dst] = f2bf(v);
      }
    }
  }
}

// ---------------- fused MLP + next-layer q (or final output) ----------------
// R22 structure; R25: pvpk deferred scatter removed (buffer eliminated).
template <int FINAL>
__global__ __launch_bounds__(256) void mlp_fused_k(const u16* __restrict__ A,
                                                   const u16* __restrict__ W0p,
                                                   const float* __restrict__ bias0,
                                                   const u16* __restrict__ W1p,
                                                   const float* __restrict__ bias1,
                                                   u16* __restrict__ xpk,
                                                   float* __restrict__ xc,
                                                   const u16* __restrict__ Wqp,
                                                   const float* __restrict__ biasq,
                                                   u16* __restrict__ qpk,
                                                   float* __restrict__ outf) {
  __shared__ u16 h0lds[8192];    // h0: 32 rows x 256 cols, A-frag layout (16KB)
  __shared__ u16 xnlds[8192];    // x_new: same layout (16KB)
  int blk = blockIdx.x;          // 2048 = MP/32
  int lane = threadIdx.x & 63;
  int wv = threadIdx.x >> 6;     // 0..3
  int rsub = wv & 1, ch = wv >> 1;
  int l15 = lane & 15, l4 = lane >> 4;

  // ---- GEMM1: rows rsub*16..+16, cols ch*128..+128, two 64-col halves ----
  const u16* Ar = A + (size_t)(blk * 32 + rsub * 16 + l15) * D_ + (l4 << 3);
  const u16* w0b = W0p + (size_t)(ch * 64) * 512 + lane * 8;
  #pragma unroll
  for (int hf = 0; hf < 2; hf++) {
    f32x4 acc1[4] = {};
    __builtin_amdgcn_s_setprio(1);
    #pragma unroll
    for (int k = 0; k < 8; k++) {
      bf16x8 a = *reinterpret_cast<const bf16x8*>(Ar + k * 32);
      #pragma unroll
      for (int ff = 0; ff < 4; ff++) {
        bf16x8 bb = *reinterpret_cast<const bf16x8*>(
            w0b + (hf * 32 + ff * 8 + k) * 512);
        acc1[ff] = __builtin_amdgcn_mfma_f32_16x16x32_bf16(a, bb, acc1[ff], 0, 0, 0);
      }
    }
    __builtin_amdgcn_s_setprio(0);
    // h0 = relu(acc1 + b0) -> h0lds in A-frag layout (static offsets)
    #pragma unroll
    for (int ff = 0; ff < 4; ff++) {
      int fc = hf * 4 + ff;
      int c = ch * 128 + fc * 16 + l15;
      float bv = bias0[c];
      int base = rsub * 4096 + (ch * 4 + (fc >> 1)) * 512 +
                 (((fc * 2 + (l15 >> 3)) & 3) * 16 + l4 * 4) * 8 + (l15 & 7);
      #pragma unroll
      for (int r = 0; r < 4; r++)
        h0lds[base + r * 8] = f2bf(fmaxf(acc1[ff][r] + bv, 0.f));
    }
  }
  __syncthreads();

  // ---- GEMM2 + light epilogue: xc residual + xnlds only ----
  const u16* w1b = W1p + (size_t)(ch * 64) * 512 + lane * 8;
  int r0g = blk * 32 + rsub * 16 + l4 * 4;
  #pragma unroll
  for (int hf = 0; hf < 2; hf++) {
    f32x4 acc2[4] = {};
    __builtin_amdgcn_s_setprio(1);
    #pragma unroll
    for (int k = 0; k < 8; k++) {
      bf16x8 a = *reinterpret_cast<const bf16x8*>(&h0lds[rsub * 4096 + k * 512 + lane * 8]);
      #pragma unroll
      for (int ff = 0; ff < 4; ff++) {
        bf16x8 bb = *reinterpret_cast<const bf16x8*>(
            w1b + (hf * 32 + ff * 8 + k) * 512);
        acc2[ff] = __builtin_amdgcn_mfma_f32_16x16x32_bf16(a, bb, acc2[ff], 0, 0, 0);
      }
    }
    __builtin_amdgcn_s_setprio(0);
    #pragma unroll
    for (int ff = 0; ff < 4; ff++) {
      int fc = hf * 4 + ff;
      int c = ch * 128 + fc * 16 + l15;
      float bv = bias1[c];
      int base = rsub * 4096 + (ch * 4 + (fc >> 1)) * 512 +
                 (((fc * 2 + (l15 >> 3)) & 3) * 16 + l4 * 4) * 8 + (l15 & 7);
      #pragma unroll
      for (int r = 0; r < 4; r++) {
        int row = r0g + r;
        float v = fmaxf(acc2[ff][r] + bv, 0.f);
        size_t o = (size_t)row * D_ + c;
        float nv = v + xc[o];
        if (!FINAL) xc[o] = nv;
        xnlds[base + r * 8] = f2bf(nv);
      }
    }
  }
  __syncthreads();

  // ---- deferred xpk copy (verbatim linear: xpk[blk<<13 + i] == xnlds[i]) ----
  if (!FINAL) {
    int tid = threadIdx.x;
    u16* dst = xpk + ((size_t)blk << 13) + tid * 8;
    #pragma unroll
    for (int i = 0; i < 4; i++)
      *reinterpret_cast<bf16x8*>(dst + i * 2048) =
          *reinterpret_cast<const bf16x8*>(&xnlds[tid * 8 + i * 2048]);
  }

  // ---- GEMM3: q(l+1) = x_new @ Wq^T + bq (or FINAL: out = x_new @ Wf^T + bf) ----
  const u16* wqb = Wqp + (size_t)(ch * 64) * 512 + lane * 8;
  #pragma unroll
  for (int hf = 0; hf < 2; hf++) {
    f32x4 acc3[4] = {};
    __builtin_amdgcn_s_setprio(1);
    #pragma unroll
    for (int k = 0; k < 8; k++) {
      bf16x8 a = *reinterpret_cast<const bf16x8*>(&xnlds[rsub * 4096 + k * 512 + lane * 8]);
      #pragma unroll
      for (int ff = 0; ff < 4; ff++) {
        bf16x8 bb = *reinterpret_cast<const bf16x8*>(
            wqb + (hf * 32 + ff * 8 + k) * 512);
        acc3[ff] = __builtin_amdgcn_mfma_f32_16x16x32_bf16(a, bb, acc3[ff], 0, 0, 0);
      }
    }
    __builtin_amdgcn_s_setprio(0);
    #pragma unroll
    for (int ff = 0; ff < 4; ff++) {
      int fc = hf * 4 + ff;
      int c = ch * 128 + fc * 16 + l15;
      float bv = biasq[c];
      #pragma unroll
      for (int r = 0; r < 4; r++) {
        int row = r0g + r;
        float v = acc3[ff][r] + bv;
        if (FINAL) {
          int b = row >> 10, i = row & (NP - 1);
          if (i < N_) outf[((size_t)b * N_ + i) * D_ + c] = v;
        } else {
          size_t dst = ((size_t)(row >> 4) << 12) + ((c >> 5) << 9) +
                       ((((c >> 3) & 3) * 16 + (row & 15)) << 3) + (c & 7);
          qpk[dst] = f2bf(v);
        }
      }
    }
  }
}

// ---------------- fused attention: Y = (mask*(sigmoid(q x^T)+eps*I)) @ x / rowsum ----------
// R27 = R25 REVERTED VERBATIM (best measured: attn ~134us, total 1554). R26
// post-mortem closed the last lever: q-in-global costs +20 VGPR (64->84,
// crossing the m69 64-step -> 4 waves/SIMD) so residency stays 2 blocks/CU
// even at 40KB LDS; q-in-LDS costs 32KB (72.5KB -> 2 blocks/CU). Both paths
// cap at 2 blocks/CU -> occupancy lever inaccessible. With tile height (R19),
// traffic (R21/R25), barrier count (R23), VALU (R24), and occupancy (R26) all
// measured, this structure's ~134us is the empirical floor.
__global__ __launch_bounds__(512) void attn_fused_k(const u16* __restrict__ qpk,
                                                    const u16* __restrict__ xpk,
                                                    const unsigned long long* __restrict__ mask,
                                                    u16* __restrict__ yb) {
  __shared__ u16 xlds[16384];          // staged xpk chunk (32KB), swizzled units
  __shared__ u16 qlds[16384];          // q for this 64-row block (32KB), swizzled
  __shared__ u16 plds[64][64];         // P single buffer, XOR-swizzled cols (8KB)
  float* dlds = (float*)xlds;          // den partials (aliases xlds, dead after loop)
  int wg = blockIdx.x;                 // 1024 = 64 b * 16 row-blocks
  int xcd = wg & 7, slot = wg >> 3;    // bijective XCD swizzle (1024 % 8 == 0)
  int b = xcd * 8 + (slot >> 4);       // 8 batches per XCD, 16 blocks/batch adjacent
  int rb = slot & 15;
  int rbase = rb * 64;
  int lane = threadIdx.x & 63;
  int wv = threadIdx.x >> 6;           // 0..7
  int rsub = wv & 3, jh = wv >> 2;     // row-subtile (16 rows), j-half (32 cols)
  int l15 = lane & 15, l4 = lane >> 4;
  int rowL = rsub * 16 + l4 * 4;       // local row base owned for sigmoid

  const u16* xpkC = xpk + (size_t)b * PKB;
  const unsigned long long* mB = mask + (size_t)b * (NP * 16);
  // plds swizzled read bases (constant per thread): col ^ ((row&7)<<3), row = rt*16+l15
  int swr = (l15 & 7) << 3;
  int pc0 = (l4 << 3) ^ swr;           // j-half 0 (kk=0)
  int pc1 = (32 | (l4 << 3)) ^ swr;    // j-half 1 (kk=1)
  // swizzled lane offset for staging source + QK reads (u16 units)
  int loff = 8 * (lane ^ (lane >> 3));
  // PV gather bases: logical = pvb + kk*8192 + ct*256 + e*8; phys = log^(x3<<3),
  // x3 = bits[8:6] = (lane>>4&1) | (((lane&15)>>3)<<1) | (ct<<2). Fold: G^(e*8).
  int pvb = ((lane >> 5) & 1) * 4096 + (wv >> 1) * 1024 + (wv & 1) * 512 +
            ((lane & 15) >> 3) * 128 + ((lane >> 4) & 1) * 64 + (lane & 7);
  int x3 = ((lane >> 4) & 1) | (((lane & 15) >> 3) << 1);
  int G00 = pvb + (x3 << 3);                    // kk0 ct0
  int G01 = pvb + 256 + ((x3 ^ 4) << 3);        // kk0 ct1
  int G10 = G00 + 8192;                         // kk1 ct0
  int G11 = G01 + 8192;                         // kk1 ct1

  f32x4 yacc[4][2] = {};               // [row-tile][col-tile], 64 rows x 32 cols
  float denp[4] = {0.f, 0.f, 0.f, 0.f};

  // ---- prologue: stage chunk 0 + q block (pre-swizzled source lanes) ----
  {
    const u16* gs = xpkC + wv * 2048 + loff;
    u16* ld = &xlds[wv * 2048];
    #pragma unroll
    for (int i = 0; i < 4; i++)
      gl_lds16(gs + i * 512, ld + i * 512);
    const u16* gq = qpk + ((((size_t)b * NP + rbase) >> 4) << 12) + wv * 2048 + loff;
    u16* lq = &qlds[wv * 2048];
    #pragma unroll
    for (int i = 0; i < 4; i++)
      gl_lds16(gq + i * 512, lq + i * 512);
  }
  __syncthreads();   // drains vmcnt -> xlds + qlds ready

  #pragma unroll 1
  for (int t = 0; t < 16; t++) {
    // ---- QK(t): my 16 rows x 32 j, A from qlds, B from xlds (swizzled loff) ----
    f32x4 sacc[2] = {};
    __builtin_amdgcn_s_setprio(1);
    #pragma unroll
    for (int k = 0; k < 8; k++) {
      bf16x8 a = *reinterpret_cast<const bf16x8*>(&qlds[rsub * 4096 + k * 512 + loff]);
      bf16x8 b0 = *reinterpret_cast<const bf16x8*>(&xlds[(16 * jh + k) * 512 + loff]);
      sacc[0] = __builtin_amdgcn_mfma_f32_16x16x32_bf16(a, b0, sacc[0], 0, 0, 0);
      bf16x8 b1 = *reinterpret_cast<const bf16x8*>(&xlds[(16 * jh + 8 + k) * 512 + loff]);
      sacc[1] = __builtin_amdgcn_mfma_f32_16x16x32_bf16(a, b1, sacc[1], 0, 0, 0);
    }
    __builtin_amdgcn_s_setprio(0);
    // ---- sigmoid + mask + eps-diag -> bf16 P in plds (swizzled) + den ----
    #pragma unroll
    for (int r = 0; r < 4; r++) {
      int i = rbase + rowL + r;
      unsigned long long mw = (i < N_) ? mB[((size_t)i << 4) + t] : 0ull;
      int swz = ((rowL + r) & 7) << 3;
      #pragma unroll
      for (int fl = 0; fl < 2; fl++) {
        int jloc = jh * 32 + fl * 16 + l15;
        int j = t * 64 + jloc;
        float w = 0.f;
        if ((mw >> jloc) & 1ull) {
          float s = __builtin_amdgcn_rcpf(1.f + __expf(-sacc[fl][r]));
          w = s + (i == j ? 1e-5f : 0.f);
        }
        u16 wq = f2bf(w);
        plds[rowL + r][jloc ^ swz] = wq;
        denp[r] += bf2f(wq);
      }
    }
    __syncthreads();   // A: plds published (all QK xlds reads also done)
    // ---- PV(t): all 64 rows, my 32 d-cols; B-frags gathered from xlds ----
    {
      const __bf16* xb16 = reinterpret_cast<const __bf16*>(xlds);
      __builtin_amdgcn_s_setprio(1);
      bf16x8 w0, w1;
      #pragma unroll
      for (int e = 0; e < 8; e++) {
        w0[e] = xb16[G00 ^ (e * 8)];
        w1[e] = xb16[G01 ^ (e * 8)];
      }
      #pragma unroll
      for (int rt = 0; rt < 4; rt++) {
        bf16x8 ap = *reinterpret_cast<const bf16x8*>(&plds[rt * 16 + l15][pc0]);
        yacc[rt][0] = __builtin_amdgcn_mfma_f32_16x16x32_bf16(ap, w0, yacc[rt][0], 0, 0, 0);
        yacc[rt][1] = __builtin_amdgcn_mfma_f32_16x16x32_bf16(ap, w1, yacc[rt][1], 0, 0, 0);
      }
      #pragma unroll
      for (int e = 0; e < 8; e++) {
        w0[e] = xb16[G10 ^ (e * 8)];
        w1[e] = xb16[G11 ^ (e * 8)];
      }
      #pragma unroll
      for (int rt = 0; rt < 4; rt++) {
        bf16x8 ap = *reinterpret_cast<const bf16x8*>(&plds[rt * 16 + l15][pc1]);
        yacc[rt][0] = __builtin_amdgcn_mfma_f32_16x16x32_bf16(ap, w0, yacc[rt][0], 0, 0, 0);
        yacc[rt][1] = __builtin_amdgcn_mfma_f32_16x16x32_bf16(ap, w1, yacc[rt][1], 0, 0, 0);
      }
      __builtin_amdgcn_s_setprio(0);
    }
    __syncthreads();   // B: all PV xlds/plds reads done -> xlds safe to overwrite
    // ---- stage chunk t+1 into xlds (pre-swizzled source lanes) ----
    if (t < 15) {
      const u16* gs = xpkC + (size_t)(t + 1) * 16384 + wv * 2048 + loff;
      u16* ld = &xlds[wv * 2048];
      #pragma unroll
      for (int i = 0; i < 4; i++)
        gl_lds16(gs + i * 512, ld + i * 512);
    }
    __syncthreads();   // C: drains vmcnt -> xlds = chunk t+1 ready; plds reusable
  }

  // ---- den: 16-lane reduce per wave -> cross-wave (jh=0/1) sum via dlds ----
  #pragma unroll
  for (int r = 0; r < 4; r++) {
    float d = denp[r];
    #pragma unroll
    for (int m = 1; m < 16; m <<= 1) d += __shfl_xor(d, m, 64);
    if (l15 == 0) dlds[wv * 16 + l4 * 4 + r] = d;
  }
  __syncthreads();
  // ---- epilogue: row-major bf16 out, my 32 d-cols of all 64 rows ----
  u16* yB = yb + ((size_t)b * NP + rbase) * D_ + wv * 32 + l15;
  #pragma unroll
  for (int rt = 0; rt < 4; rt++) {
    #pragma unroll
    for (int r = 0; r < 4; r++) {
      int rl = rt * 16 + l4 * 4 + r;
      int i = rbase + rl;
      float den = dlds[rt * 16 + l4 * 4 + r] + dlds[(rt + 4) * 16 + l4 * 4 + r];
      float inv = (i < N_ && den > 0.f) ? 1.f / den : 0.f;
      #pragma unroll
      for (int ct = 0; ct < 2; ct++)
        yB[(size_t)rl * D_ + ct * 16] = f2bf(yacc[rt][ct][r] * inv);
    }
  }
}

extern "C" void kernel_launch(void* const* d_in, const int* in_sizes, int n_in,
                              void* d_out, int out_size, void* d_ws, size_t ws_size,
                              hipStream_t stream) {
  const float* x   = (const float*)d_in[0];
  const float* adj = (const float*)d_in[1];
  const float* Wa  = (const float*)d_in[2];
  const float* ba  = (const float*)d_in[3];
  const float* W0  = (const float*)d_in[4];
  const float* b0_ = (const float*)d_in[5];
  const float* W1  = (const float*)d_in[6];
  const float* b1_ = (const float*)d_in[7];
  const float* Wf  = (const float*)d_in[8];
  const float* bff = (const float*)d_in[9];
  float* out = (float*)d_out;

  char* p = (char*)d_ws;
  auto alloc = [&](size_t bytes) {
    char* r = p;
    p += (bytes + 255) & ~(size_t)255;
    return r;
  };
  unsigned long long* mask = (unsigned long long*)alloc((size_t)B_ * NP * 16 * 8);
  u16* xb    = (u16*)alloc((size_t)MP * D_ * 2);   // prologue only
  u16* xpk   = (u16*)alloc((size_t)B_ * PKB * 2);  // x: QK-B frags == linear-A frags
  u16* qpk   = (u16*)alloc((size_t)MP * D_ * 2);   // q, A-frag-packed
  u16* slotB = (u16*)alloc((size_t)MP * D_ * 2);   // attn out, row-major
  float* xc  = (float*)alloc((size_t)MP * D_ * 4);
  u16* wb    = (u16*)alloc((size_t)(3 * L_ + 1) * D_ * D_ * 2);

  pack_mask_k<<<dim3(B_ * N_), dim3(64), 0, stream>>>(adj, mask);
  conv_w_k<<<dim3(704), dim3(256), 0, stream>>>(Wa, W0, W1, Wf, wb);
  prep_x_k<<<dim3((B_ * N_ * D_ + 255) / 256), dim3(256), 0, stream>>>(x, xc, xb);
  pack_x_k<<<dim3(16, 4, B_), dim3(256), 0, stream>>>(xb, xpk);

  // q for layer 0
  linear_k<4, 1><<<dim3(MP / 64, D_ / 64), dim3(256), 0, stream>>>(
      xpk, wb, ba, qpk, nullptr, nullptr, nullptr);

  for (int l = 0; l < L_; l++) {
    const u16* w0l = wb + (size_t)(L_ + l) * D_ * D_;
    const u16* w1l = wb + (size_t)(2 * L_ + l) * D_ * D_;

    attn_fused_k<<<dim3(1024), dim3(512), 0, stream>>>(
        qpk, xpk, mask, slotB);
    if (l < L_ - 1) {
      mlp_fused_k<0><<<dim3(2048), dim3(256), 0, stream>>>(
          slotB, w0l, b0_ + l * D_, w1l, b1_ + l * D_, xpk, xc,
          wb + (size_t)(l + 1) * D_ * D_, ba + (l + 1) * D_, qpk, nullptr);
    } else {
      mlp_fused_k<1><<<dim3(2048), dim3(256), 0, stream>>>(
          slotB, w0l, b0_ + l * D_, w1l, b1_ + l * D_, xpk, xc,
          wb + (size_t)3 * L_ * D_ * D_, bff, nullptr, out);
    }
  }
}

// Round 17
// 1452.929 us; speedup vs baseline: 1.3415x; 1.0709x over previous
//
#include <hip/hip_runtime.h>
#include <hip/hip_bf16.h>

#define B_ 64
#define N_ 1000
#define NP 1024
#define D_ 256
#define L_ 7
#define MP (B_*NP)        // 65536 padded rows total
#define PKB 262144        // u16 elements per batch in packed operand buffers

typedef unsigned short u16;
typedef __attribute__((ext_vector_type(4))) float f32x4;
typedef __bf16 bf16x8 __attribute__((ext_vector_type(8)));

static __device__ __forceinline__ u16 f2bf(float f) {
  __hip_bfloat16 h = __float2bfloat16(f);
  return *reinterpret_cast<u16*>(&h);
}
static __device__ __forceinline__ float bf2f(u16 u) {
  __hip_bfloat16 h;
  *reinterpret_cast<u16*>(&h) = u;
  return __bfloat162float(h);
}

// async global->LDS 16B copy: LDS dest is wave-uniform base (HW adds lane*16)
static __device__ __forceinline__ void gl_lds16(const u16* g, u16* l) {
  __builtin_amdgcn_global_load_lds(
      (const __attribute__((address_space(1))) void*)g,
      (__attribute__((address_space(3))) void*)l, 16, 0, 0);
}

// ---------------- pack adjacency into bitmask (diag forced on) ----------------
__global__ __launch_bounds__(64) void pack_mask_k(const float* __restrict__ adj,
                                                  unsigned long long* __restrict__ mask) {
  int row = blockIdx.x;              // b*N_ + i
  int b = row / N_, i = row - b * N_;
  int lane = threadIdx.x;            // 64 threads
  const float* arow = adj + (size_t)(b * N_ + i) * N_;
  #pragma unroll
  for (int j0 = 0; j0 < NP; j0 += 64) {
    int j = j0 + lane;
    bool on = (j < N_) && (arow[j] != 0.0f || j == i);
    unsigned long long m = __ballot(on);
    if (lane == 0) mask[((size_t)(b * NP + i)) * 16 + (j0 >> 6)] = m;
  }
}

// ---------------- convert weights to bf16 in MFMA-fragment-packed layout ----------------
__global__ __launch_bounds__(256) void conv_w_k(const float* __restrict__ Wa,
                                                const float* __restrict__ W0,
                                                const float* __restrict__ W1,
                                                const float* __restrict__ Wf,
                                                u16* __restrict__ wpk) {
  int T = blockIdx.x * 256 + threadIdx.x;   // one 16B frag-slot
  const int NW = 3 * L_ + 1;
  if (T >= NW * 128 * 64) return;
  int lane = T & 63;
  int fid = T >> 6;
  int k = fid & 7, f = (fid >> 3) & 3, by = (fid >> 5) & 3, w = fid >> 7;
  const float* src;
  if (w < L_) src = Wa + (size_t)w * D_ * D_;
  else if (w < 2 * L_) src = W0 + (size_t)(w - L_) * D_ * D_;
  else if (w < 3 * L_) src = W1 + (size_t)(w - 2 * L_) * D_ * D_;
  else src = Wf;
  int row = by * 64 + f * 16 + (lane & 15);
  int col = k * 32 + ((lane >> 4) << 3);
  const float* s = src + (size_t)row * D_ + col;
  u16 out8[8];
  #pragma unroll
  for (int e = 0; e < 8; e++) out8[e] = f2bf(s[e]);
  *reinterpret_cast<bf16x8*>(wpk + (size_t)T * 8) =
      *reinterpret_cast<bf16x8*>(out8);
}

// ---------------- fused prologue: x fp32 -> xc (padded fp32) + xpk (bf16 frags) ----------
// R28: prep_x_k merged into pack_x_k. Reads x directly (coalesced fp32 rows),
// writes the padded fp32 master copy xc AND the bf16 tile to LDS, then frag-
// packs to xpk exactly as before. Eliminates the xb intermediate (32MB W +
// 32MB R) and one dispatch. Same f2bf rounding + same xc values -> bitwise-
// identical downstream. Tiles (cc,bd,b) cover all of [0,NP)x[0,D_) -> full xc
// coverage incl. zeroed pad rows.
__global__ __launch_bounds__(256) void pack_x_k(const float* __restrict__ x,
                                                float* __restrict__ xc,
                                                u16* __restrict__ xpk) {
  __shared__ u16 t[64][65];
  int b = blockIdx.z;
  int cc = blockIdx.x;               // j-chunk index (16)
  int bd = blockIdx.y;               // 64-wide d block (4)
  int i0 = cc * 64, d0 = bd * 64;
  int tid = threadIdx.x;
  int tx = tid & 63, ty = tid >> 6;
  const float* srcx = x + (size_t)b * N_ * D_;
  float* dxc = xc + (size_t)b * NP * D_;
  #pragma unroll
  for (int r = ty; r < 64; r += 4) {
    int i = i0 + r;
    float v = (i < N_) ? srcx[(size_t)i * D_ + d0 + tx] : 0.f;
    dxc[(size_t)i * D_ + d0 + tx] = v;
    t[r][tx] = f2bf(v);                // t[j-local][d-local]
  }
  __syncthreads();
  int lane = tid & 63, q = tid >> 6;
  int l4 = lane >> 4, l15 = lane & 15;
  u16* dstq = xpk + (size_t)b * PKB;
  #pragma unroll
  for (int kk = 0; kk < 2; kk++) {
    int frag = cc * 32 + q * 8 + (2 * bd + kk);
    bf16x8 v;
    #pragma unroll
    for (int e = 0; e < 8; e++)
      v[e] = *reinterpret_cast<const __bf16*>(&t[l15 + 16 * q][kk * 32 + (l4 << 3) + e]);
    *reinterpret_cast<bf16x8*>(dstq + (size_t)frag * 512 + lane * 8) = v;
  }
}

// ---------------- generic linear: y = A @ W.T + bias (W fragment-packed) ----------------
// MODE 4: A-frag-packed out (q). APK: A fragment-packed. (Only used for layer-0 q.)
template <int MODE, int APK>
__global__ __launch_bounds__(256) void linear_k(const u16* __restrict__ A,
                                                const u16* __restrict__ W,   // packed
                                                const float* __restrict__ bias,
                                                u16* __restrict__ outb,
                                                float* __restrict__ xc,
                                                u16* __restrict__ xbp,
                                                float* __restrict__ outf) {
  int lane = threadIdx.x & 63;
  int wv = threadIdx.x >> 6;
  int rbase = blockIdx.x * 64 + wv * 16;
  int cbase = blockIdx.y * 64;
  f32x4 acc[4] = {};
  const u16* Ar;
  if (APK) Ar = A + ((size_t)(rbase >> 4) << 12) + lane * 8;
  else     Ar = A + (size_t)(rbase + (lane & 15)) * D_ + ((lane >> 4) << 3);
  const u16* Wr = W + (size_t)blockIdx.y * (32 * 512) + lane * 8;   // coalesced frags
  #pragma unroll
  for (int k = 0; k < 8; k++) {
    bf16x8 a = APK ? *reinterpret_cast<const bf16x8*>(Ar + k * 512)
                   : *reinterpret_cast<const bf16x8*>(Ar + k * 32);
    #pragma unroll
    for (int f = 0; f < 4; f++) {
      bf16x8 bb = *reinterpret_cast<const bf16x8*>(Wr + (f * 8 + k) * 512);
      acc[f] = __builtin_amdgcn_mfma_f32_16x16x32_bf16(a, bb, acc[f], 0, 0, 0);
    }
  }
  int r0 = rbase + ((lane >> 4) << 2);
  int col = cbase + (lane & 15);
  #pragma unroll
  for (int f = 0; f < 4; f++) {
    int c = col + f * 16;
    float bv = bias[c];
    #pragma unroll
    for (int r = 0; r < 4; r++) {
      int row = r0 + r;
      float v = acc[f][r] + bv;
      if (MODE == 3) {
        int b = row >> 10, i = row & (NP - 1);
        if (i < N_) outf[((size_t)b * N_ + i) * D_ + c] = v;
      } else {  // MODE 4
        size_t dst = ((size_t)(row >> 4) << 12) + ((c >> 5) << 9) +
                     ((((c >> 3) & 3) * 16 + (row & 15)) << 3) + (c & 7);
        outb[dst] = f2bf(v);
      }
    }
  }
}

// ---------------- fused MLP + next-layer q (or final output) ----------------
// R22 structure; R25: pvpk deferred scatter removed (buffer eliminated).
template <int FINAL>
__global__ __launch_bounds__(256) void mlp_fused_k(const u16* __restrict__ A,
                                                   const u16* __restrict__ W0p,
                                                   const float* __restrict__ bias0,
                                                   const u16* __restrict__ W1p,
                                                   const float* __restrict__ bias1,
                                                   u16* __restrict__ xpk,
                                                   float* __restrict__ xc,
                                                   const u16* __restrict__ Wqp,
                                                   const float* __restrict__ biasq,
                                                   u16* __restrict__ qpk,
                                                   float* __restrict__ outf) {
  __shared__ u16 h0lds[8192];    // h0: 32 rows x 256 cols, A-frag layout (16KB)
  __shared__ u16 xnlds[8192];    // x_new: same layout (16KB)
  int blk = blockIdx.x;          // 2048 = MP/32
  int lane = threadIdx.x & 63;
  int wv = threadIdx.x >> 6;     // 0..3
  int rsub = wv & 1, ch = wv >> 1;
  int l15 = lane & 15, l4 = lane >> 4;

  // ---- GEMM1: rows rsub*16..+16, cols ch*128..+128, two 64-col halves ----
  const u16* Ar = A + (size_t)(blk * 32 + rsub * 16 + l15) * D_ + (l4 << 3);
  const u16* w0b = W0p + (size_t)(ch * 64) * 512 + lane * 8;
  #pragma unroll
  for (int hf = 0; hf < 2; hf++) {
    f32x4 acc1[4] = {};
    __builtin_amdgcn_s_setprio(1);
    #pragma unroll
    for (int k = 0; k < 8; k++) {
      bf16x8 a = *reinterpret_cast<const bf16x8*>(Ar + k * 32);
      #pragma unroll
      for (int ff = 0; ff < 4; ff++) {
        bf16x8 bb = *reinterpret_cast<const bf16x8*>(
            w0b + (hf * 32 + ff * 8 + k) * 512);
        acc1[ff] = __builtin_amdgcn_mfma_f32_16x16x32_bf16(a, bb, acc1[ff], 0, 0, 0);
      }
    }
    __builtin_amdgcn_s_setprio(0);
    // h0 = relu(acc1 + b0) -> h0lds in A-frag layout (static offsets)
    #pragma unroll
    for (int ff = 0; ff < 4; ff++) {
      int fc = hf * 4 + ff;
      int c = ch * 128 + fc * 16 + l15;
      float bv = bias0[c];
      int base = rsub * 4096 + (ch * 4 + (fc >> 1)) * 512 +
                 (((fc * 2 + (l15 >> 3)) & 3) * 16 + l4 * 4) * 8 + (l15 & 7);
      #pragma unroll
      for (int r = 0; r < 4; r++)
        h0lds[base + r * 8] = f2bf(fmaxf(acc1[ff][r] + bv, 0.f));
    }
  }
  __syncthreads();

  // ---- GEMM2 + light epilogue: xc residual + xnlds only ----
  const u16* w1b = W1p + (size_t)(ch * 64) * 512 + lane * 8;
  int r0g = blk * 32 + rsub * 16 + l4 * 4;
  #pragma unroll
  for (int hf = 0; hf < 2; hf++) {
    f32x4 acc2[4] = {};
    __builtin_amdgcn_s_setprio(1);
    #pragma unroll
    for (int k = 0; k < 8; k++) {
      bf16x8 a = *reinterpret_cast<const bf16x8*>(&h0lds[rsub * 4096 + k * 512 + lane * 8]);
      #pragma unroll
      for (int ff = 0; ff < 4; ff++) {
        bf16x8 bb = *reinterpret_cast<const bf16x8*>(
            w1b + (hf * 32 + ff * 8 + k) * 512);
        acc2[ff] = __builtin_amdgcn_mfma_f32_16x16x32_bf16(a, bb, acc2[ff], 0, 0, 0);
      }
    }
    __builtin_amdgcn_s_setprio(0);
    #pragma unroll
    for (int ff = 0; ff < 4; ff++) {
      int fc = hf * 4 + ff;
      int c = ch * 128 + fc * 16 + l15;
      float bv = bias1[c];
      int base = rsub * 4096 + (ch * 4 + (fc >> 1)) * 512 +
                 (((fc * 2 + (l15 >> 3)) & 3) * 16 + l4 * 4) * 8 + (l15 & 7);
      #pragma unroll
      for (int r = 0; r < 4; r++) {
        int row = r0g + r;
        float v = fmaxf(acc2[ff][r] + bv, 0.f);
        size_t o = (size_t)row * D_ + c;
        float nv = v + xc[o];
        if (!FINAL) xc[o] = nv;
        xnlds[base + r * 8] = f2bf(nv);
      }
    }
  }
  __syncthreads();

  // ---- deferred xpk copy (verbatim linear: xpk[blk<<13 + i] == xnlds[i]) ----
  if (!FINAL) {
    int tid = threadIdx.x;
    u16* dst = xpk + ((size_t)blk << 13) + tid * 8;
    #pragma unroll
    for (int i = 0; i < 4; i++)
      *reinterpret_cast<bf16x8*>(dst + i * 2048) =
          *reinterpret_cast<const bf16x8*>(&xnlds[tid * 8 + i * 2048]);
  }

  // ---- GEMM3: q(l+1) = x_new @ Wq^T + bq (or FINAL: out = x_new @ Wf^T + bf) ----
  const u16* wqb = Wqp + (size_t)(ch * 64) * 512 + lane * 8;
  #pragma unroll
  for (int hf = 0; hf < 2; hf++) {
    f32x4 acc3[4] = {};
    __builtin_amdgcn_s_setprio(1);
    #pragma unroll
    for (int k = 0; k < 8; k++) {
      bf16x8 a = *reinterpret_cast<const bf16x8*>(&xnlds[rsub * 4096 + k * 512 + lane * 8]);
      #pragma unroll
      for (int ff = 0; ff < 4; ff++) {
        bf16x8 bb = *reinterpret_cast<const bf16x8*>(
            wqb + (hf * 32 + ff * 8 + k) * 512);
        acc3[ff] = __builtin_amdgcn_mfma_f32_16x16x32_bf16(a, bb, acc3[ff], 0, 0, 0);
      }
    }
    __builtin_amdgcn_s_setprio(0);
    #pragma unroll
    for (int ff = 0; ff < 4; ff++) {
      int fc = hf * 4 + ff;
      int c = ch * 128 + fc * 16 + l15;
      float bv = biasq[c];
      #pragma unroll
      for (int r = 0; r < 4; r++) {
        int row = r0g + r;
        float v = acc3[ff][r] + bv;
        if (FINAL) {
          int b = row >> 10, i = row & (NP - 1);
          if (i < N_) outf[((size_t)b * N_ + i) * D_ + c] = v;
        } else {
          size_t dst = ((size_t)(row >> 4) << 12) + ((c >> 5) << 9) +
                       ((((c >> 3) & 3) * 16 + (row & 15)) << 3) + (c & 7);
          qpk[dst] = f2bf(v);
        }
      }
    }
  }
}

// ---------------- fused attention: Y = (mask*(sigmoid(q x^T)+eps*I)) @ x / rowsum ----------
// R25 structure, 2x-verified best (~134us/dispatch, total 1554/1556). Stall
// model closed (R16 post-mortem): per-CU LDS-pipe work ~ 41TB/s ~ 90% of the
// practical b128-mix ceiling (m134) -> attn is LDS-throughput-bound. All other
// levers measured null/negative: tile height (R19), traffic (R21/R25),
// barriers (R23), occupancy (R26: q-in-global needs 84 VGPR, q-in-LDS needs
// 32KB -> both cap at 2 blocks/CU).
__global__ __launch_bounds__(512) void attn_fused_k(const u16* __restrict__ qpk,
                                                    const u16* __restrict__ xpk,
                                                    const unsigned long long* __restrict__ mask,
                                                    u16* __restrict__ yb) {
  __shared__ u16 xlds[16384];          // staged xpk chunk (32KB), swizzled units
  __shared__ u16 qlds[16384];          // q for this 64-row block (32KB), swizzled
  __shared__ u16 plds[64][64];         // P single buffer, XOR-swizzled cols (8KB)
  float* dlds = (float*)xlds;          // den partials (aliases xlds, dead after loop)
  int wg = blockIdx.x;                 // 1024 = 64 b * 16 row-blocks
  int xcd = wg & 7, slot = wg >> 3;    // bijective XCD swizzle (1024 % 8 == 0)
  int b = xcd * 8 + (slot >> 4);       // 8 batches per XCD, 16 blocks/batch adjacent
  int rb = slot & 15;
  int rbase = rb * 64;
  int lane = threadIdx.x & 63;
  int wv = threadIdx.x >> 6;           // 0..7
  int rsub = wv & 3, jh = wv >> 2;     // row-subtile (16 rows), j-half (32 cols)
  int l15 = lane & 15, l4 = lane >> 4;
  int rowL = rsub * 16 + l4 * 4;       // local row base owned for sigmoid

  const u16* xpkC = xpk + (size_t)b * PKB;
  const unsigned long long* mB = mask + (size_t)b * (NP * 16);
  // plds swizzled read bases (constant per thread): col ^ ((row&7)<<3), row = rt*16+l15
  int swr = (l15 & 7) << 3;
  int pc0 = (l4 << 3) ^ swr;           // j-half 0 (kk=0)
  int pc1 = (32 | (l4 << 3)) ^ swr;    // j-half 1 (kk=1)
  // swizzled lane offset for staging source + QK reads (u16 units)
  int loff = 8 * (lane ^ (lane >> 3));
  // PV gather bases: logical = pvb + kk*8192 + ct*256 + e*8; phys = log^(x3<<3),
  // x3 = bits[8:6] = (lane>>4&1) | (((lane&15)>>3)<<1) | (ct<<2). Fold: G^(e*8).
  int pvb = ((lane >> 5) & 1) * 4096 + (wv >> 1) * 1024 + (wv & 1) * 512 +
            ((lane & 15) >> 3) * 128 + ((lane >> 4) & 1) * 64 + (lane & 7);
  int x3 = ((lane >> 4) & 1) | (((lane & 15) >> 3) << 1);
  int G00 = pvb + (x3 << 3);                    // kk0 ct0
  int G01 = pvb + 256 + ((x3 ^ 4) << 3);        // kk0 ct1
  int G10 = G00 + 8192;                         // kk1 ct0
  int G11 = G01 + 8192;                         // kk1 ct1

  f32x4 yacc[4][2] = {};               // [row-tile][col-tile], 64 rows x 32 cols
  float denp[4] = {0.f, 0.f, 0.f, 0.f};

  // ---- prologue: stage chunk 0 + q block (pre-swizzled source lanes) ----
  {
    const u16* gs = xpkC + wv * 2048 + loff;
    u16* ld = &xlds[wv * 2048];
    #pragma unroll
    for (int i = 0; i < 4; i++)
      gl_lds16(gs + i * 512, ld + i * 512);
    const u16* gq = qpk + ((((size_t)b * NP + rbase) >> 4) << 12) + wv * 2048 + loff;
    u16* lq = &qlds[wv * 2048];
    #pragma unroll
    for (int i = 0; i < 4; i++)
      gl_lds16(gq + i * 512, lq + i * 512);
  }
  __syncthreads();   // drains vmcnt -> xlds + qlds ready

  #pragma unroll 1
  for (int t = 0; t < 16; t++) {
    // ---- QK(t): my 16 rows x 32 j, A from qlds, B from xlds (swizzled loff) ----
    f32x4 sacc[2] = {};
    __builtin_amdgcn_s_setprio(1);
    #pragma unroll
    for (int k = 0; k < 8; k++) {
      bf16x8 a = *reinterpret_cast<const bf16x8*>(&qlds[rsub * 4096 + k * 512 + loff]);
      bf16x8 b0 = *reinterpret_cast<const bf16x8*>(&xlds[(16 * jh + k) * 512 + loff]);
      sacc[0] = __builtin_amdgcn_mfma_f32_16x16x32_bf16(a, b0, sacc[0], 0, 0, 0);
      bf16x8 b1 = *reinterpret_cast<const bf16x8*>(&xlds[(16 * jh + 8 + k) * 512 + loff]);
      sacc[1] = __builtin_amdgcn_mfma_f32_16x16x32_bf16(a, b1, sacc[1], 0, 0, 0);
    }
    __builtin_amdgcn_s_setprio(0);
    // ---- sigmoid + mask + eps-diag -> bf16 P in plds (swizzled) + den ----
    #pragma unroll
    for (int r = 0; r < 4; r++) {
      int i = rbase + rowL + r;
      unsigned long long mw = (i < N_) ? mB[((size_t)i << 4) + t] : 0ull;
      int swz = ((rowL + r) & 7) << 3;
      #pragma unroll
      for (int fl = 0; fl < 2; fl++) {
        int jloc = jh * 32 + fl * 16 + l15;
        int j = t * 64 + jloc;
        float w = 0.f;
        if ((mw >> jloc) & 1ull) {
          float s = __builtin_amdgcn_rcpf(1.f + __expf(-sacc[fl][r]));
          w = s + (i == j ? 1e-5f : 0.f);
        }
        u16 wq = f2bf(w);
        plds[rowL + r][jloc ^ swz] = wq;
        denp[r] += bf2f(wq);
      }
    }
    __syncthreads();   // A: plds published (all QK xlds reads also done)
    // ---- PV(t): all 64 rows, my 32 d-cols; B-frags gathered from xlds ----
    {
      const __bf16* xb16 = reinterpret_cast<const __bf16*>(xlds);
      __builtin_amdgcn_s_setprio(1);
      bf16x8 w0, w1;
      #pragma unroll
      for (int e = 0; e < 8; e++) {
        w0[e] = xb16[G00 ^ (e * 8)];
        w1[e] = xb16[G01 ^ (e * 8)];
      }
      #pragma unroll
      for (int rt = 0; rt < 4; rt++) {
        bf16x8 ap = *reinterpret_cast<const bf16x8*>(&plds[rt * 16 + l15][pc0]);
        yacc[rt][0] = __builtin_amdgcn_mfma_f32_16x16x32_bf16(ap, w0, yacc[rt][0], 0, 0, 0);
        yacc[rt][1] = __builtin_amdgcn_mfma_f32_16x16x32_bf16(ap, w1, yacc[rt][1], 0, 0, 0);
      }
      #pragma unroll
      for (int e = 0; e < 8; e++) {
        w0[e] = xb16[G10 ^ (e * 8)];
        w1[e] = xb16[G11 ^ (e * 8)];
      }
      #pragma unroll
      for (int rt = 0; rt < 4; rt++) {
        bf16x8 ap = *reinterpret_cast<const bf16x8*>(&plds[rt * 16 + l15][pc1]);
        yacc[rt][0] = __builtin_amdgcn_mfma_f32_16x16x32_bf16(ap, w0, yacc[rt][0], 0, 0, 0);
        yacc[rt][1] = __builtin_amdgcn_mfma_f32_16x16x32_bf16(ap, w1, yacc[rt][1], 0, 0, 0);
      }
      __builtin_amdgcn_s_setprio(0);
    }
    __syncthreads();   // B: all PV xlds/plds reads done -> xlds safe to overwrite
    // ---- stage chunk t+1 into xlds (pre-swizzled source lanes) ----
    if (t < 15) {
      const u16* gs = xpkC + (size_t)(t + 1) * 16384 + wv * 2048 + loff;
      u16* ld = &xlds[wv * 2048];
      #pragma unroll
      for (int i = 0; i < 4; i++)
        gl_lds16(gs + i * 512, ld + i * 512);
    }
    __syncthreads();   // C: drains vmcnt -> xlds = chunk t+1 ready; plds reusable
  }

  // ---- den: 16-lane reduce per wave -> cross-wave (jh=0/1) sum via dlds ----
  #pragma unroll
  for (int r = 0; r < 4; r++) {
    float d = denp[r];
    #pragma unroll
    for (int m = 1; m < 16; m <<= 1) d += __shfl_xor(d, m, 64);
    if (l15 == 0) dlds[wv * 16 + l4 * 4 + r] = d;
  }
  __syncthreads();
  // ---- epilogue: row-major bf16 out, my 32 d-cols of all 64 rows ----
  u16* yB = yb + ((size_t)b * NP + rbase) * D_ + wv * 32 + l15;
  #pragma unroll
  for (int rt = 0; rt < 4; rt++) {
    #pragma unroll
    for (int r = 0; r < 4; r++) {
      int rl = rt * 16 + l4 * 4 + r;
      int i = rbase + rl;
      float den = dlds[rt * 16 + l4 * 4 + r] + dlds[(rt + 4) * 16 + l4 * 4 + r];
      float inv = (i < N_ && den > 0.f) ? 1.f / den : 0.f;
      #pragma unroll
      for (int ct = 0; ct < 2; ct++)
        yB[(size_t)rl * D_ + ct * 16] = f2bf(yacc[rt][ct][r] * inv);
    }
  }
}

extern "C" void kernel_launch(void* const* d_in, const int* in_sizes, int n_in,
                              void* d_out, int out_size, void* d_ws, size_t ws_size,
                              hipStream_t stream) {
  const float* x   = (const float*)d_in[0];
  const float* adj = (const float*)d_in[1];
  const float* Wa  = (const float*)d_in[2];
  const float* ba  = (const float*)d_in[3];
  const float* W0  = (const float*)d_in[4];
  const float* b0_ = (const float*)d_in[5];
  const float* W1  = (const float*)d_in[6];
  const float* b1_ = (const float*)d_in[7];
  const float* Wf  = (const float*)d_in[8];
  const float* bff = (const float*)d_in[9];
  float* out = (float*)d_out;

  char* p = (char*)d_ws;
  auto alloc = [&](size_t bytes) {
    char* r = p;
    p += (bytes + 255) & ~(size_t)255;
    return r;
  };
  unsigned long long* mask = (unsigned long long*)alloc((size_t)B_ * NP * 16 * 8);
  u16* xpk   = (u16*)alloc((size_t)B_ * PKB * 2);  // x: QK-B frags == linear-A frags
  u16* qpk   = (u16*)alloc((size_t)MP * D_ * 2);   // q, A-frag-packed
  u16* slotB = (u16*)alloc((size_t)MP * D_ * 2);   // attn out, row-major
  float* xc  = (float*)alloc((size_t)MP * D_ * 4);
  u16* wb    = (u16*)alloc((size_t)(3 * L_ + 1) * D_ * D_ * 2);

  pack_mask_k<<<dim3(B_ * N_), dim3(64), 0, stream>>>(adj, mask);
  conv_w_k<<<dim3(704), dim3(256), 0, stream>>>(Wa, W0, W1, Wf, wb);
  pack_x_k<<<dim3(16, 4, B_), dim3(256), 0, stream>>>(x, xc, xpk);

  // q for layer 0
  linear_k<4, 1><<<dim3(MP / 64, D_ / 64), dim3(256), 0, stream>>>(
      xpk, wb, ba, qpk, nullptr, nullptr, nullptr);

  for (int l = 0; l < L_; l++) {
    const u16* w0l = wb + (size_t)(L_ + l) * D_ * D_;
    const u16* w1l = wb + (size_t)(2 * L_ + l) * D_ * D_;

    attn_fused_k<<<dim3(1024), dim3(512), 0, stream>>>(
        qpk, xpk, mask, slotB);
    if (l < L_ - 1) {
      mlp_fused_k<0><<<dim3(2048), dim3(256), 0, stream>>>(
          slotB, w0l, b0_ + l * D_, w1l, b1_ + l * D_, xpk, xc,
          wb + (size_t)(l + 1) * D_ * D_, ba + (l + 1) * D_, qpk, nullptr);
    } else {
      mlp_fused_k<1><<<dim3(2048), dim3(256), 0, stream>>>(
          slotB, w0l, b0_ + l * D_, w1l, b1_ + l * D_, xpk, xc,
          wb + (size_t)3 * L_ * D_ * D_, bff, nullptr, out);
    }
  }
}